// Round 21
// baseline (1485.334 us; speedup 1.0000x reference)
//
#include <hip/hip_runtime.h>
#include <hip/hip_cooperative_groups.h>
#include <cmath>

namespace cg = cooperative_groups;

#define T_STEPS 512
#define NBLK 256

typedef _Float16 h8 __attribute__((ext_vector_type(8)));
typedef float f4 __attribute__((ext_vector_type(4)));
typedef int i32x4 __attribute__((ext_vector_type(4)));
typedef unsigned long long ull_t;

__device__ __forceinline__ float sigm(float v) { return 1.f / (1.f + __expf(-v)); }
__device__ __forceinline__ float tanh_fast(float v) { return 1.f - 2.f / (__expf(2.f * v) + 1.f); }

// ---------------- pack P = emb @ [Wx interleaved] + bias : [513][4096] fp32 (exact input path)
__global__ void pack_P(const float* __restrict__ emb,
                       const float* __restrict__ Wgx, const float* __restrict__ Wix,
                       const float* __restrict__ Wfx, const float* __restrict__ Wox,
                       const float* __restrict__ bg, const float* __restrict__ bi,
                       const float* __restrict__ bf_, const float* __restrict__ bo,
                       float* __restrict__ P) {
  __shared__ float es[8][512];
  const int vg = blockIdx.x;   // 0..64
  const int st = blockIdx.y;   // 0..15
  const int tid = threadIdx.x;
  for (int i = tid; i < 8 * 512; i += 256) {
    int vv = i >> 9, k = i & 511;
    int v = vg * 8 + vv;
    es[vv][k] = (v < 513) ? emb[v * 512 + k] : 0.f;
  }
  __syncthreads();
  const int c = st * 256 + tid;
  const int gate = c & 3, unit = c >> 2;
  const float* W = gate == 0 ? Wgx : gate == 1 ? Wix : gate == 2 ? Wfx : Wox;
  const float* bias = gate == 0 ? bg : gate == 1 ? bi : gate == 2 ? bf_ : bo;
  float acc[8];
  const float bv = bias[unit];
#pragma unroll
  for (int vv = 0; vv < 8; vv++) acc[vv] = bv;
  for (int k = 0; k < 512; k++) {
    float w = W[k * 1024 + unit];
#pragma unroll
    for (int vv = 0; vv < 8; vv++) acc[vv] += es[vv][k] * w;
  }
#pragma unroll
  for (int vv = 0; vv < 8; vv++) {
    int v = vg * 8 + vv;
    if (v < 513) P[(size_t)v * 4096 + c] = acc[vv];
  }
}

// ---------------- pack Wt[c][k] = W_{gate(c)}h[k][unit(c)] as fp16
__global__ void pack_Wt(const float* __restrict__ Wgh, const float* __restrict__ Wih,
                        const float* __restrict__ Wfh, const float* __restrict__ Woh,
                        _Float16* __restrict__ Wt) {
  const int c = blockIdx.x;
  const int gate = c & 3, unit = c >> 2;
  const float* W = gate == 0 ? Wgh : gate == 1 ? Wih : gate == 2 ? Wfh : Woh;
  for (int k = threadIdx.x; k < 1024; k += 256)
    Wt[(size_t)c * 1024 + k] = (_Float16)W[k * 1024 + unit];
}

// ---------------- persistent LSTM: 8 independent row-groups of 16 batch rows.
// Sync = LSB step-tag seqlock (R16/R17). Split-K across waves with swapped
// MFMA operands (R17). NEW: PER-WAVE staging. Wave w verify-loads its OWN
// 4KB K-slice (h[16 rows][128w..+128), produced by only 4 blocks) into a
// WAVE-PRIVATE LDS buffer -- no staging barrier; same-wave lgkmcnt orders
// write->fragment-read. Waves start MFMA as soon as their 4 producers are
// ready; producer skew hides under other waves' compute. The two barriers
// bracket only the part[] write:
//   stage(own)+MFMA -> BAR_A -> part write -> BAR_B -> reduce+gates+publish.
// Single part[] buffer WAR-safe: every wave's part(t-1) reads precede its
// arrival at BAR_A(t) (program order), so writes(t) after BAR_A(t) are safe.
// wlds is wave-private: no cross-wave access, self WAR ordered by lgkmcnt.
__launch_bounds__(512, 2)
__global__ void lstm_step_all(const int* __restrict__ x,
                              const float* __restrict__ P,
                              const _Float16* __restrict__ Wt,
                              _Float16* __restrict__ hbuf,
                              float* __restrict__ h32,
                              const float* __restrict__ h_init,
                              const float* __restrict__ c_init) {
  cg::grid_group grid = cg::this_grid();
  __shared__ _Float16 wlds[8 * 2048];    // 32 KB: per-wave 16 rows x 128 fp16 (quad-swizzled)
  __shared__ float part[8 * 16 * 132];   // 67.6 KB split-K partials
  const int tid = threadIdx.x;
  const int blk = blockIdx.x;
  const int grp = blk & 7;      // row-group
  const int sub = blk >> 3;     // 0..31 col-partition
  const int lane = tid & 63;
  const int wid = tid >> 6;     // wave = K-slice owner
  const int l15 = lane & 15;
  const int gg = lane >> 4;
  const int kg = gg * 8;
  const int colbase = sub * 128;  // gate-col base
  const int ubase = sub * 32;     // hidden-unit base
  const int rowbase = grp * 16;   // batch-row base

  // Wt fragments (MFMA *A* operand): wave w, col-tile ct, k-step ks
  h8 wfr[32];
  {
    const _Float16* wp = Wt + (size_t)(colbase + l15) * 1024 + wid * 128 + kg;
#pragma unroll
    for (int ct = 0; ct < 8; ct++)
#pragma unroll
      for (int ks = 0; ks < 4; ks++)
        wfr[ct * 4 + ks] = *(const h8*)(wp + (size_t)ct * 16 * 1024 + ks * 32);
  }

  // init: h0 (LSB cleared -> tag 0) into buffer 0; tag-1 junk into buffer 1
  if (tid < 128) {
    int r16 = tid >> 3, q = tid & 7;
    union { _Float16 h[4]; ull_t u; } pk;
#pragma unroll
    for (int u = 0; u < 4; u++) pk.h[u] = (_Float16)h_init[ubase + q * 4 + u];
    pk.u &= 0xFFFEFFFEFFFEFFFEull;  // force tag 0
    *(ull_t*)&hbuf[(size_t)(rowbase + r16) * 1024 + ubase + q * 4] = pk.u;
    *(ull_t*)&hbuf[(size_t)(128 * 1024) + (size_t)(rowbase + r16) * 1024 + ubase + q * 4] =
        0x0001000100010001ull;  // buffer 1: tag-1 junk (ws poison has LSB 0!)
  }
  // gate-phase identity: row = tid>>5, unit = tid&31 (persistent c state)
  const int grow = tid >> 5;
  const int gu = tid & 31;
  float cst = c_init[ubase + gu];
  // per-wave staging geometry: 4 load instrs j=0..3; instr j covers rows
  // 4j..4j+3 (row = 4j + (lane>>4)), granule q = lane&15 (16B); 256B/row.
  const int srow0 = lane >> 4;    // row offset within 4-row group
  const int sq = lane & 15;       // granule index
  grid.sync();  // covers h0/junk, Wt/P reads

  for (int t = 0; t < T_STEPS; t++) {
    const _Float16* hc = hbuf + (t & 1) * (128 * 1024);
    _Float16* hn = hbuf + ((t + 1) & 1) * (128 * 1024);

    // exact-P gather issued early (x then P, cache-warm plain loads)
    const int xv = x[(rowbase + grow) * 513 + t];
    const float* prow = P + (size_t)xv * 4096 + colbase + gu * 4;
    f4 pv = *(const f4*)(prow);

    // ---- per-wave tag-verified load of own 4KB K-slice (4-producer gating)
    const int tagm = (int)(0x00010001u * (unsigned)((t >> 1) & 1));
    i32x4 av0, av1, av2, av3;
    {
      const _Float16* p0 = &hc[(size_t)(rowbase + 0 + srow0) * 1024 + wid * 128 + sq * 8];
      const _Float16* p1 = &hc[(size_t)(rowbase + 4 + srow0) * 1024 + wid * 128 + sq * 8];
      const _Float16* p2 = &hc[(size_t)(rowbase + 8 + srow0) * 1024 + wid * 128 + sq * 8];
      const _Float16* p3 = &hc[(size_t)(rowbase + 12 + srow0) * 1024 + wid * 128 + sq * 8];
      for (;;) {
        asm volatile("global_load_dwordx4 %0, %1, off sc0 sc1"
                     : "=v"(av0) : "v"(p0) : "memory");
        asm volatile("global_load_dwordx4 %0, %1, off sc0 sc1"
                     : "=v"(av1) : "v"(p1) : "memory");
        asm volatile("global_load_dwordx4 %0, %1, off sc0 sc1"
                     : "=v"(av2) : "v"(p2) : "memory");
        asm volatile("global_load_dwordx4 %0, %1, off sc0 sc1"
                     : "=v"(av3) : "v"(p3) : "memory");
        asm volatile("s_waitcnt vmcnt(0)" ::: "memory");
        bool ok = true;
#pragma unroll
        for (int j = 0; j < 4; j++) {
          ok &= ((av0[j] & 0x00010001) == tagm);
          ok &= ((av1[j] & 0x00010001) == tagm);
          ok &= ((av2[j] & 0x00010001) == tagm);
          ok &= ((av3[j] & 0x00010001) == tagm);
        }
        if (__ballot(ok) == ~0ull) break;
        __builtin_amdgcn_s_sleep(1);
      }
    }
    __builtin_amdgcn_sched_barrier(0);
    // wave-private LDS write, quad-swizzled: pos q' = q ^ (row&7)
    {
      const int wbase = wid * 2048;
      *(i32x4*)&wlds[wbase + (0 + srow0) * 128 + ((sq ^ ((0 + srow0) & 7)) * 8)] = av0;
      *(i32x4*)&wlds[wbase + (4 + srow0) * 128 + ((sq ^ ((4 + srow0) & 7)) * 8)] = av1;
      *(i32x4*)&wlds[wbase + (8 + srow0) * 128 + ((sq ^ ((8 + srow0) & 7)) * 8)] = av2;
      *(i32x4*)&wlds[wbase + (12 + srow0) * 128 + ((sq ^ ((12 + srow0) & 7)) * 8)] = av3;
    }
    // fragment read (same wave -- compiler inserts lgkmcnt, no barrier)
    h8 hfr[4];
#pragma unroll
    for (int ks = 0; ks < 4; ks++)
      hfr[ks] = *(const h8*)&wlds[wid * 2048 + l15 * 128 + (((ks * 4 + gg) ^ (l15 & 7)) * 8)];

    // ---- MFMA, operands swapped: acc[ct][i] = pre[row l15][col ct*16+4gg+i]
    f4 acc[8];
#pragma unroll
    for (int ct = 0; ct < 8; ct++) {
      acc[ct] = (f4){0.f, 0.f, 0.f, 0.f};
#pragma unroll
      for (int ks = 0; ks < 4; ks++)
        acc[ct] = __builtin_amdgcn_mfma_f32_16x16x32_f16(wfr[ct * 4 + ks], hfr[ks],
                                                         acc[ct], 0, 0, 0);
    }
    __syncthreads();  // BAR_A: all waves done reading part (step t-1)
    // partial store: one b128 per col-tile (4 consecutive cols of row l15)
#pragma unroll
    for (int ct = 0; ct < 8; ct++)
      *(f4*)&part[(wid * 16 + l15) * 132 + ct * 16 + 4 * gg] = acc[ct];
    __syncthreads();  // BAR_B: partials ready

    // ---- reduce + gates: thread (grow, gu) sums 8 K-slices + exact-P
    {
      f4 q = pv;
#pragma unroll
      for (int w = 0; w < 8; w++)
        q += *(const f4*)&part[(w * 16 + grow) * 132 + gu * 4];
      float g_ = tanh_fast(q[0]);
      float i_ = sigm(q[1]);
      float f_ = sigm(q[2]);
      float o_ = sigm(q[3]);
      cst = g_ * i_ + cst * f_;
      float hv = tanh_fast(cst) * o_;
      if (t == T_STEPS - 1) {
        h32[(size_t)(rowbase + grow) * 1024 + ubase + gu] = hv;
      } else {
        const unsigned tagn = (unsigned)(((t + 1) >> 1) & 1);
        union { _Float16 hh; unsigned short us; } cv;
        cv.hh = (_Float16)hv;
        unsigned v0 = ((unsigned)cv.us & 0xFFFEu) | tagn;
        unsigned v1 = (unsigned)__shfl_down((int)v0, 1);
        unsigned lo = (v0 & 0xffffu) | (v1 << 16);
        unsigned lo2 = (unsigned)__shfl_down((int)lo, 2);
        if ((gu & 3) == 0) {
          ull_t pv8 = (ull_t)lo | ((ull_t)lo2 << 32);
          __hip_atomic_store((ull_t*)&hn[(size_t)(rowbase + grow) * 1024 + ubase + gu],
                             pv8, __ATOMIC_RELAXED, __HIP_MEMORY_SCOPE_AGENT);
        }
      }
    }
  }
}

// ---------------- fused projection + log_softmax: 128 blocks x 512 threads
__global__ void proj_lsm(const float* __restrict__ h32, const float* __restrict__ Wph,
                         const float* __restrict__ bp, float* __restrict__ out) {
  __shared__ float red[8];
  const int b = blockIdx.x;
  const int tid = threadIdx.x;
  const float* hrow = h32 + b * 1024;
  float acc = bp[tid];
#pragma unroll 4
  for (int k = 0; k < 1024; k++) acc += hrow[k] * Wph[k * 512 + tid];
  float m = acc;
  for (int o = 1; o < 64; o <<= 1) m = fmaxf(m, __shfl_xor(m, o, 64));
  if ((tid & 63) == 0) red[tid >> 6] = m;
  __syncthreads();
  m = red[0];
#pragma unroll
  for (int i = 1; i < 8; i++) m = fmaxf(m, red[i]);
  __syncthreads();  // all reads of red done before reuse
  float e = expf(acc - m);
  float s = e;
  for (int o = 1; o < 64; o <<= 1) s += __shfl_xor(s, o, 64);
  if ((tid & 63) == 0) red[tid >> 6] = s;
  __syncthreads();
  s = 0.f;
#pragma unroll
  for (int i = 0; i < 8; i++) s += red[i];
  out[b * 512 + tid] = acc - (logf(s) + m);
}

extern "C" void kernel_launch(void* const* d_in, const int* in_sizes, int n_in,
                              void* d_out, int out_size, void* d_ws, size_t ws_size,
                              hipStream_t stream) {
  const int* x = (const int*)d_in[0];
  const float* emb = (const float*)d_in[1];
  const float* Wgx = (const float*)d_in[2];
  const float* Wgh = (const float*)d_in[3];
  const float* bg = (const float*)d_in[4];
  const float* Wix = (const float*)d_in[5];
  const float* Wih = (const float*)d_in[6];
  const float* bi = (const float*)d_in[7];
  const float* Wfx = (const float*)d_in[8];
  const float* Wfh = (const float*)d_in[9];
  const float* bf = (const float*)d_in[10];
  const float* Wox = (const float*)d_in[11];
  const float* Woh = (const float*)d_in[12];
  const float* bo = (const float*)d_in[13];
  const float* Wph = (const float*)d_in[14];
  const float* bp = (const float*)d_in[15];
  const float* h_init = (const float*)d_in[16];
  const float* c_init = (const float*)d_in[17];

  char* ws = (char*)d_ws;
  float* P = (float*)ws;                                   // 520*4096*4   = 8,519,680
  _Float16* Wt = (_Float16*)(ws + 8519680);                // 4096*1024*2  = 8,388,608
  _Float16* hbuf = (_Float16*)(ws + 8519680 + 8388608);    // 2*128*1024*2 = 524,288
  float* h32 = (float*)(ws + 8519680 + 8388608 + 524288);  // 128*1024*4   = 524,288

  pack_P<<<dim3(65, 16), 256, 0, stream>>>(emb, Wgx, Wix, Wfx, Wox, bg, bi, bf, bo, P);
  pack_Wt<<<4096, 256, 0, stream>>>(Wgh, Wih, Wfh, Woh, Wt);

  void* args[] = {(void*)&x, (void*)&P, (void*)&Wt, (void*)&hbuf,
                  (void*)&h32, (void*)&h_init, (void*)&c_init};
  hipLaunchCooperativeKernel((void*)lstm_step_all, dim3(NBLK), dim3(512), args, 0, stream);

  proj_lsm<<<128, 512, 0, stream>>>(h32, Wph, bp, (float*)d_out);
}

// Round 22
// 1384.196 us; speedup vs baseline: 1.0731x; 1.0731x over previous
//
#include <hip/hip_runtime.h>
#include <hip/hip_cooperative_groups.h>
#include <cmath>

namespace cg = cooperative_groups;

#define T_STEPS 512
#define NBLK 256

typedef _Float16 h8 __attribute__((ext_vector_type(8)));
typedef float f4 __attribute__((ext_vector_type(4)));
typedef int i32x4 __attribute__((ext_vector_type(4)));
typedef unsigned long long ull_t;

__device__ __forceinline__ float sigm(float v) { return 1.f / (1.f + __expf(-v)); }
__device__ __forceinline__ float tanh_fast(float v) { return 1.f - 2.f / (__expf(2.f * v) + 1.f); }

// ---------------- pack P = emb @ [Wx interleaved] + bias : [513][4096] fp32 (exact input path)
__global__ void pack_P(const float* __restrict__ emb,
                       const float* __restrict__ Wgx, const float* __restrict__ Wix,
                       const float* __restrict__ Wfx, const float* __restrict__ Wox,
                       const float* __restrict__ bg, const float* __restrict__ bi,
                       const float* __restrict__ bf_, const float* __restrict__ bo,
                       float* __restrict__ P) {
  __shared__ float es[8][512];
  const int vg = blockIdx.x;   // 0..64
  const int st = blockIdx.y;   // 0..15
  const int tid = threadIdx.x;
  for (int i = tid; i < 8 * 512; i += 256) {
    int vv = i >> 9, k = i & 511;
    int v = vg * 8 + vv;
    es[vv][k] = (v < 513) ? emb[v * 512 + k] : 0.f;
  }
  __syncthreads();
  const int c = st * 256 + tid;
  const int gate = c & 3, unit = c >> 2;
  const float* W = gate == 0 ? Wgx : gate == 1 ? Wix : gate == 2 ? Wfx : Wox;
  const float* bias = gate == 0 ? bg : gate == 1 ? bi : gate == 2 ? bf_ : bo;
  float acc[8];
  const float bv = bias[unit];
#pragma unroll
  for (int vv = 0; vv < 8; vv++) acc[vv] = bv;
  for (int k = 0; k < 512; k++) {
    float w = W[k * 1024 + unit];
#pragma unroll
    for (int vv = 0; vv < 8; vv++) acc[vv] += es[vv][k] * w;
  }
#pragma unroll
  for (int vv = 0; vv < 8; vv++) {
    int v = vg * 8 + vv;
    if (v < 513) P[(size_t)v * 4096 + c] = acc[vv];
  }
}

// ---------------- pack Wt[c][k] = W_{gate(c)}h[k][unit(c)] as fp16
__global__ void pack_Wt(const float* __restrict__ Wgh, const float* __restrict__ Wih,
                        const float* __restrict__ Wfh, const float* __restrict__ Woh,
                        _Float16* __restrict__ Wt) {
  const int c = blockIdx.x;
  const int gate = c & 3, unit = c >> 2;
  const float* W = gate == 0 ? Wgh : gate == 1 ? Wih : gate == 2 ? Wfh : Woh;
  for (int k = threadIdx.x; k < 1024; k += 256)
    Wt[(size_t)c * 1024 + k] = (_Float16)W[k * 1024 + unit];
}

// ---------------- persistent LSTM: 8 independent row-groups of 16 batch rows.
// = CHAMPION (R17/R20). Sync = LSB step-tag seqlock: h_t in buffer t&1,
// every fp16 LSB = (t>>1)&1; producers store 8B sc1 (no drain/flag); consumers
// tag-verify coalesced loads and retry. Split-K across waves with SWAPPED
// MFMA operands (wave w owns K-slice [128w,+128) for all 128 cols; partials
// land as b128 per col-tile). 2 barriers/step.
__launch_bounds__(512, 2)
__global__ void lstm_step_all(const int* __restrict__ x,
                              const float* __restrict__ P,
                              const _Float16* __restrict__ Wt,
                              _Float16* __restrict__ hbuf,
                              float* __restrict__ h32,
                              const float* __restrict__ h_init,
                              const float* __restrict__ c_init) {
  cg::grid_group grid = cg::this_grid();
  __shared__ _Float16 alds[16 * 1024];   // 32 KB staged A (granule-XOR swizzled)
  __shared__ float part[8 * 16 * 132];   // 67.6 KB split-K partials
  const int tid = threadIdx.x;
  const int blk = blockIdx.x;
  const int grp = blk & 7;      // row-group
  const int sub = blk >> 3;     // 0..31 col-partition
  const int lane = tid & 63;
  const int wid = tid >> 6;     // wave = K-slice owner
  const int l15 = lane & 15;
  const int gg = lane >> 4;
  const int kg = gg * 8;
  const int colbase = sub * 128;  // gate-col base
  const int ubase = sub * 32;     // hidden-unit base
  const int rowbase = grp * 16;   // batch-row base
  const int arow = tid >> 5;      // staging row (0..15), 32 threads per row
  const int agb = tid & 31;       // staging granule base (16B granules)

  // Wt fragments (MFMA *A* operand): wave w, col-tile ct, k-step ks
  h8 wfr[32];
  {
    const _Float16* wp = Wt + (size_t)(colbase + l15) * 1024 + wid * 128 + kg;
#pragma unroll
    for (int ct = 0; ct < 8; ct++)
#pragma unroll
      for (int ks = 0; ks < 4; ks++)
        wfr[ct * 4 + ks] = *(const h8*)(wp + (size_t)ct * 16 * 1024 + ks * 32);
  }

  // init: h0 (LSB cleared -> tag 0) into buffer 0; tag-1 junk into buffer 1
  if (tid < 128) {
    int r16 = tid >> 3, q = tid & 7;
    union { _Float16 h[4]; ull_t u; } pk;
#pragma unroll
    for (int u = 0; u < 4; u++) pk.h[u] = (_Float16)h_init[ubase + q * 4 + u];
    pk.u &= 0xFFFEFFFEFFFEFFFEull;  // force tag 0
    *(ull_t*)&hbuf[(size_t)(rowbase + r16) * 1024 + ubase + q * 4] = pk.u;
    *(ull_t*)&hbuf[(size_t)(128 * 1024) + (size_t)(rowbase + r16) * 1024 + ubase + q * 4] =
        0x0001000100010001ull;  // buffer 1: tag-1 junk (ws poison has LSB 0!)
  }
  // gate-phase identity: row = tid>>5, unit = tid&31 (persistent c state)
  const int grow = tid >> 5;
  const int gu = tid & 31;
  float cst = c_init[ubase + gu];
  // swizzled LDS base for staging writes (granule XOR on low 3 bits)
  const int abase = arow * 1024 + ((agb ^ (arow & 7)) * 8);
  grid.sync();  // covers h0/junk, Wt/P reads

  for (int t = 0; t < T_STEPS; t++) {
    const _Float16* hc = hbuf + (t & 1) * (128 * 1024);
    _Float16* hn = hbuf + ((t + 1) & 1) * (128 * 1024);

    // exact-P gather issued early (x then P, cache-warm plain loads)
    const int xv = x[(rowbase + grow) * 513 + t];
    const float* prow = P + (size_t)xv * 4096 + colbase + gu * 4;
    f4 pv = *(const f4*)(prow);

    // ---- A-stage with tag verification (the only inter-block sync)
    const int tagm = (int)(0x00010001u * (unsigned)((t >> 1) & 1));
    i32x4 av0, av1, av2, av3;
    {
      const _Float16* pbase = &hc[(size_t)(rowbase + arow) * 1024 + agb * 8];
      for (;;) {
        asm volatile("global_load_dwordx4 %0, %1, off sc0 sc1"
                     : "=v"(av0) : "v"(pbase) : "memory");
        asm volatile("global_load_dwordx4 %0, %1, off offset:512 sc0 sc1"
                     : "=v"(av1) : "v"(pbase) : "memory");
        asm volatile("global_load_dwordx4 %0, %1, off offset:1024 sc0 sc1"
                     : "=v"(av2) : "v"(pbase) : "memory");
        asm volatile("global_load_dwordx4 %0, %1, off offset:1536 sc0 sc1"
                     : "=v"(av3) : "v"(pbase) : "memory");
        asm volatile("s_waitcnt vmcnt(0)" ::: "memory");
        bool ok = true;
#pragma unroll
        for (int j = 0; j < 4; j++) {
          ok &= ((av0[j] & 0x00010001) == tagm);
          ok &= ((av1[j] & 0x00010001) == tagm);
          ok &= ((av2[j] & 0x00010001) == tagm);
          ok &= ((av3[j] & 0x00010001) == tagm);
        }
        if (ok) break;
        __builtin_amdgcn_s_sleep(1);
      }
    }
    __builtin_amdgcn_sched_barrier(0);
    *(i32x4*)&alds[abase] = av0;
    *(i32x4*)&alds[abase + 256] = av1;  // +32 granules = +256 fp16
    *(i32x4*)&alds[abase + 512] = av2;
    *(i32x4*)&alds[abase + 768] = av3;
    __syncthreads();  // BAR1: alds ready

    // ---- h fragments (MFMA *B* operand): wave's own K-slice only, 4 b128
    h8 hfr[4];
#pragma unroll
    for (int ks = 0; ks < 4; ks++) {
      int g = wid * 16 + ks * 4 + gg;
      hfr[ks] = *(const h8*)&alds[l15 * 1024 + ((g ^ (l15 & 7)) * 8)];
    }

    // ---- MFMA, operands swapped: acc[ct][i] = pre[row l15][col ct*16+4gg+i]
    f4 acc[8];
#pragma unroll
    for (int ct = 0; ct < 8; ct++) {
      acc[ct] = (f4){0.f, 0.f, 0.f, 0.f};
#pragma unroll
      for (int ks = 0; ks < 4; ks++)
        acc[ct] = __builtin_amdgcn_mfma_f32_16x16x32_f16(wfr[ct * 4 + ks], hfr[ks],
                                                         acc[ct], 0, 0, 0);
    }
    // partial store: one b128 per col-tile (4 consecutive cols of row l15)
#pragma unroll
    for (int ct = 0; ct < 8; ct++)
      *(f4*)&part[(wid * 16 + l15) * 132 + ct * 16 + 4 * gg] = acc[ct];
    __syncthreads();  // BAR2: partials ready

    // ---- reduce + gates: thread (grow, gu) sums 8 K-slices + exact-P
    {
      f4 q = pv;
#pragma unroll
      for (int w = 0; w < 8; w++)
        q += *(const f4*)&part[(w * 16 + grow) * 132 + gu * 4];
      float g_ = tanh_fast(q[0]);
      float i_ = sigm(q[1]);
      float f_ = sigm(q[2]);
      float o_ = sigm(q[3]);
      cst = g_ * i_ + cst * f_;
      float hv = tanh_fast(cst) * o_;
      if (t == T_STEPS - 1) {
        h32[(size_t)(rowbase + grow) * 1024 + ubase + gu] = hv;
      } else {
        const unsigned tagn = (unsigned)(((t + 1) >> 1) & 1);
        union { _Float16 hh; unsigned short us; } cv;
        cv.hh = (_Float16)hv;
        unsigned v0 = ((unsigned)cv.us & 0xFFFEu) | tagn;
        unsigned v1 = (unsigned)__shfl_down((int)v0, 1);
        unsigned lo = (v0 & 0xffffu) | (v1 << 16);
        unsigned lo2 = (unsigned)__shfl_down((int)lo, 2);
        if ((gu & 3) == 0) {
          ull_t pv8 = (ull_t)lo | ((ull_t)lo2 << 32);
          __hip_atomic_store((ull_t*)&hn[(size_t)(rowbase + grow) * 1024 + ubase + gu],
                             pv8, __ATOMIC_RELAXED, __HIP_MEMORY_SCOPE_AGENT);
        }
      }
    }
  }
}

// ---------------- fused projection + log_softmax: 128 blocks x 512 threads
__global__ void proj_lsm(const float* __restrict__ h32, const float* __restrict__ Wph,
                         const float* __restrict__ bp, float* __restrict__ out) {
  __shared__ float red[8];
  const int b = blockIdx.x;
  const int tid = threadIdx.x;
  const float* hrow = h32 + b * 1024;
  float acc = bp[tid];
#pragma unroll 4
  for (int k = 0; k < 1024; k++) acc += hrow[k] * Wph[k * 512 + tid];
  float m = acc;
  for (int o = 1; o < 64; o <<= 1) m = fmaxf(m, __shfl_xor(m, o, 64));
  if ((tid & 63) == 0) red[tid >> 6] = m;
  __syncthreads();
  m = red[0];
#pragma unroll
  for (int i = 1; i < 8; i++) m = fmaxf(m, red[i]);
  __syncthreads();  // all reads of red done before reuse
  float e = expf(acc - m);
  float s = e;
  for (int o = 1; o < 64; o <<= 1) s += __shfl_xor(s, o, 64);
  if ((tid & 63) == 0) red[tid >> 6] = s;
  __syncthreads();
  s = 0.f;
#pragma unroll
  for (int i = 0; i < 8; i++) s += red[i];
  out[b * 512 + tid] = acc - (logf(s) + m);
}

extern "C" void kernel_launch(void* const* d_in, const int* in_sizes, int n_in,
                              void* d_out, int out_size, void* d_ws, size_t ws_size,
                              hipStream_t stream) {
  const int* x = (const int*)d_in[0];
  const float* emb = (const float*)d_in[1];
  const float* Wgx = (const float*)d_in[2];
  const float* Wgh = (const float*)d_in[3];
  const float* bg = (const float*)d_in[4];
  const float* Wix = (const float*)d_in[5];
  const float* Wih = (const float*)d_in[6];
  const float* bi = (const float*)d_in[7];
  const float* Wfx = (const float*)d_in[8];
  const float* Wfh = (const float*)d_in[9];
  const float* bf = (const float*)d_in[10];
  const float* Wox = (const float*)d_in[11];
  const float* Woh = (const float*)d_in[12];
  const float* bo = (const float*)d_in[13];
  const float* Wph = (const float*)d_in[14];
  const float* bp = (const float*)d_in[15];
  const float* h_init = (const float*)d_in[16];
  const float* c_init = (const float*)d_in[17];

  char* ws = (char*)d_ws;
  float* P = (float*)ws;                                   // 520*4096*4   = 8,519,680
  _Float16* Wt = (_Float16*)(ws + 8519680);                // 4096*1024*2  = 8,388,608
  _Float16* hbuf = (_Float16*)(ws + 8519680 + 8388608);    // 2*128*1024*2 = 524,288
  float* h32 = (float*)(ws + 8519680 + 8388608 + 524288);  // 128*1024*4   = 524,288

  pack_P<<<dim3(65, 16), 256, 0, stream>>>(emb, Wgx, Wix, Wfx, Wox, bg, bi, bf, bo, P);
  pack_Wt<<<4096, 256, 0, stream>>>(Wgh, Wih, Wfh, Woh, Wt);

  void* args[] = {(void*)&x, (void*)&P, (void*)&Wt, (void*)&hbuf,
                  (void*)&h32, (void*)&h_init, (void*)&c_init};
  hipLaunchCooperativeKernel((void*)lstm_step_all, dim3(NBLK), dim3(512), args, 0, stream);

  proj_lsm<<<128, 512, 0, stream>>>(h32, Wph, bp, (float*)d_out);
}